// Round 6
// baseline (591.568 us; speedup 1.0000x reference)
//
#include <hip/hip_runtime.h>
#include <stdint.h>

// MAHA decoder block, MI355X/gfx950. Round 6: V^T-as-GEMM, pool/head fusion.
// B=2, N=2048, D=1024, H=16(dh=64), L=3, R=2, HID=2734(->2816), fp32 I/O.

#define B_   2
#define N_   2048
#define D_   1024
#define H_   16
#define DH_  64
#define HID_ 2734
#define HIDP 2816
#define CNT  (B_*N_*D_)   // 4194304
#define LOG2E 1.4426950408889634f

typedef unsigned short u16;
typedef __attribute__((ext_vector_type(8))) short short8;
typedef __attribute__((ext_vector_type(4))) float f32x4;
typedef __attribute__((ext_vector_type(4))) uint16_t u16x4;

__device__ __forceinline__ u16 f2bf(float f) {
  uint32_t u = __builtin_bit_cast(uint32_t, f);
  u += 0x7fffu + ((u >> 16) & 1u);          // RNE
  return (u16)(u >> 16);
}
__device__ __forceinline__ float bf2f(u16 h) {
  uint32_t u = ((uint32_t)h) << 16;
  return __builtin_bit_cast(float, u);
}
__device__ __forceinline__ uint32_t pkbf(float a, float b) {
  return (uint32_t)f2bf(a) | ((uint32_t)f2bf(b) << 16);
}
__device__ __forceinline__ void gload_lds16(const void* g, void* l) {
  __builtin_amdgcn_global_load_lds(
      (const __attribute__((address_space(1))) uint32_t*)g,
      (__attribute__((address_space(3))) uint32_t*)l, 16, 0, 0);
}

// ============ batched weight prep: all fp32->bf16 transposes + Wdec convert + SC zero ====
__global__ __launch_bounds__(256) void wprep_k(const float* __restrict__ Wdec, const float* __restrict__ Wq,
                                               const float* __restrict__ Wk, const float* __restrict__ Wv,
                                               const float* __restrict__ Wo, const float* __restrict__ Wg,
                                               const float* __restrict__ Wu, const float* __restrict__ Wdn,
                                               u16* __restrict__ A_wp, u16* __restrict__ WdecB,
                                               u16* __restrict__ WoT, u16* __restrict__ BTgu,
                                               u16* __restrict__ WdnT, float* __restrict__ SCb) {
  const int bid = blockIdx.x;
  if (bid >= 18688) {
    if (bid == 18688 && threadIdx.x < 64) SCb[threadIdx.x] = 0.f;
    int i = (bid - 18688)*1024 + threadIdx.x*4;
    float4 v = *(const float4*)(Wdec + i);
    u16x4 o; o[0]=f2bf(v.x); o[1]=f2bf(v.y); o[2]=f2bf(v.z); o[3]=f2bf(v.w);
    *(u16x4*)(WdecB + i) = o;
    return;
  }
  const float* src; u16* dst; int K, N, KP; float scale; int imode; int bx, by;
  if (bid < 9216) {
    int j = bid >> 10, t = bid & 1023; bx = t & 31; by = t >> 5;
    int l = j / 3, which = j - l*3;
    src = which==0 ? Wq + (size_t)l*1048576 : which==1 ? Wk + (size_t)l*1048576 : Wv;
    dst = A_wp + (size_t)(l*3072 + which*1024)*1024;
    K = 1024; N = 1024; KP = 1024; scale = (which==0) ? 0.125f*LOG2E : 1.f; imode = 0;
  } else if (bid < 10240) {
    int t = bid - 9216; bx = t & 31; by = t >> 5;
    src = Wo; dst = WoT; K=1024; N=1024; KP=1024; scale=1.f; imode=0;
  } else if (bid < 13056) {
    int t = bid - 10240; bx = t % 88; by = t / 88;
    src = Wg; dst = BTgu; K=1024; N=HID_; KP=1024; scale=1.f; imode=1;
  } else if (bid < 15872) {
    int t = bid - 13056; bx = t % 88; by = t / 88;
    src = Wu; dst = BTgu; K=1024; N=HID_; KP=1024; scale=1.f; imode=2;
  } else {
    int t = bid - 15872; bx = t & 31; by = t >> 5;
    src = Wdn; dst = WdnT; K=HID_; N=1024; KP=HIDP; scale=1.f; imode=0;
  }
  __shared__ float tt[32][33];
  const int tx = threadIdx.x & 31, ty = threadIdx.x >> 5;
  const int nb = bx*32, kb = by*32;
  #pragma unroll
  for (int i = 0; i < 4; i++) {
    int k = kb + ty + i*8, n = nb + tx;
    tt[ty + i*8][tx] = (k < K && n < N) ? src[(size_t)k * N + n] * scale : 0.f;
  }
  __syncthreads();
  #pragma unroll
  for (int i = 0; i < 4; i++) {
    int n = nb + ty + i*8, k = kb + tx;
    int r;
    if (imode == 0) r = n;
    else if (imode == 1) r = ((n>>4)<<5) + (n&15);
    else r = ((n>>4)<<5) + 16 + (n&15);
    dst[(size_t)r * KP + k] = f2bf(tt[tx][ty + i*8]);
  }
}

// ---------------- attention RMSNorm: 4 rows per block + both pooled levels (fp32) -------
__global__ __launch_bounds__(256) void rmsA_k(const float* __restrict__ x, const float* __restrict__ w,
                                              u16* __restrict__ xn, u16* __restrict__ xp1,
                                              u16* __restrict__ xp2) {
  const int j = blockIdx.x;                       // rows 4j..4j+3
  const float* xr = x + (size_t)(4*j) * D_;
  float a[4][4], wv[4];
  float ss[4] = {0.f, 0.f, 0.f, 0.f};
  #pragma unroll
  for (int i = 0; i < 4; i++) {
    int c = threadIdx.x + i*256;
    wv[i] = w[c];
    #pragma unroll
    for (int r = 0; r < 4; r++) { float v = xr[(size_t)r*D_ + c]; a[r][i] = v; ss[r] += v*v; }
  }
  #pragma unroll
  for (int o = 1; o < 64; o <<= 1) {
    #pragma unroll
    for (int r = 0; r < 4; r++) ss[r] += __shfl_xor(ss[r], o);
  }
  __shared__ float red[4][4];
  if ((threadIdx.x & 63) == 0) {
    #pragma unroll
    for (int r = 0; r < 4; r++) red[threadIdx.x >> 6][r] = ss[r];
  }
  __syncthreads();
  float sc[4];
  #pragma unroll
  for (int r = 0; r < 4; r++)
    sc[r] = rsqrtf((red[0][r]+red[1][r]+red[2][r]+red[3][r]) * (1.f/D_) + 1e-6f);
  #pragma unroll
  for (int i = 0; i < 4; i++) {
    int c = threadIdx.x + i*256;
    float v0 = a[0][i]*wv[i]*sc[0], v1 = a[1][i]*wv[i]*sc[1];
    float v2 = a[2][i]*wv[i]*sc[2], v3 = a[3][i]*wv[i]*sc[3];
    xn[(size_t)(4*j  )*D_ + c] = f2bf(v0);
    xn[(size_t)(4*j+1)*D_ + c] = f2bf(v1);
    xn[(size_t)(4*j+2)*D_ + c] = f2bf(v2);
    xn[(size_t)(4*j+3)*D_ + c] = f2bf(v3);
    xp1[(size_t)(2*j  )*D_ + c] = f2bf(0.5f*(v0+v1));
    xp1[(size_t)(2*j+1)*D_ + c] = f2bf(0.5f*(v2+v3));
    xp2[(size_t)j*D_ + c] = f2bf(0.25f*(v0+v1+v2+v3));
  }
}

// ---------------- MFMA GEMM, C = A[M,K] * BT[N,K]^T; block = MT*32 x 128 ----------------
// MODE 1: bf16 store. MODE 2: fp32 out = SCp[11]*X1 + SCp[12]*acc. MODE 3: silu(gate)*up
template<int MT, int MODE>
__global__ __launch_bounds__(256) void gemm_t(const u16* __restrict__ A, const u16* __restrict__ BT,
                                              void* __restrict__ Cv, const float* __restrict__ X1,
                                              const float* __restrict__ SCp,
                                              int N, int K, int t1, int t2, unsigned int bt_stride) {
  __shared__ __align__(16) u16 As[MT*32*32];
  __shared__ __align__(16) u16 Bs[128*32];
  const int tid = threadIdx.x;
  const int lane = tid & 63, wid = tid >> 6;
  const int quad = lane >> 4, c16 = lane & 15;
  const int y = blockIdx.y;
  const int m0 = y * (MT*32), n0 = blockIdx.x * 128;
  const int wm = wid >> 1, wn = wid & 1;
  const int level = (y >= t2) ? 2 : ((y >= t1) ? 1 : 0);
  BT += (size_t)level * bt_stride;

  f32x4 acc[MT][4];
  #pragma unroll
  for (int i = 0; i < MT; i++)
    #pragma unroll
    for (int j = 0; j < 4; j++) acc[i][j] = f32x4{0.f,0.f,0.f,0.f};

  const int srow = lane >> 2;
  const int schunk = lane & 3;
  for (int k0 = 0; k0 < K; k0 += 32) {
    #pragma unroll
    for (int t = 0; t < MT/2; t++) {
      int idx = wid*(MT/2) + t;
      int row = idx*16 + srow;
      int g = (schunk ^ ((row >> 1) & 3)) * 8;
      gload_lds16(A + (size_t)(m0+row)*K + k0 + g, As + idx*512);
    }
    #pragma unroll
    for (int t = 0; t < 2; t++) {
      int idx = wid*2 + t;
      int row = idx*16 + srow;
      int g = (schunk ^ ((row >> 1) & 3)) * 8;
      gload_lds16(BT + (size_t)(n0+row)*K + k0 + g, Bs + idx*512);
    }
    __syncthreads();
    short8 af[MT], bfr[4];
    #pragma unroll
    for (int mt = 0; mt < MT; mt++) {
      int ar = wm*(MT*16) + mt*16 + c16;
      af[mt]  = *(const short8*)(As + ar*32 + (quad ^ ((ar>>1)&3))*8);
    }
    #pragma unroll
    for (int nt = 0; nt < 4; nt++) {
      int br = wn*64 + nt*16 + c16;
      bfr[nt] = *(const short8*)(Bs + br*32 + (quad ^ ((br>>1)&3))*8);
    }
    #pragma unroll
    for (int mt = 0; mt < MT; mt++)
      #pragma unroll
      for (int nt = 0; nt < 4; nt++)
        acc[mt][nt] = __builtin_amdgcn_mfma_f32_16x16x32_bf16(af[mt], bfr[nt], acc[mt][nt], 0, 0, 0);
    __syncthreads();
  }
  if (MODE == 1) {
    u16* C = (u16*)Cv;
    #pragma unroll
    for (int mt = 0; mt < MT; mt++)
      #pragma unroll
      for (int nt = 0; nt < 4; nt++)
        #pragma unroll
        for (int r = 0; r < 4; r++) {
          int row = m0 + wm*(MT*16) + mt*16 + quad*4 + r;
          int col = n0 + wn*64 + nt*16 + c16;
          C[(size_t)row * N + col] = f2bf(acc[mt][nt][r]);
        }
  } else if (MODE == 2) {
    float* C = (float*)Cv;
    const float q0 = SCp[11], q1 = SCp[12];
    #pragma unroll
    for (int mt = 0; mt < MT; mt++)
      #pragma unroll
      for (int nt = 0; nt < 4; nt++)
        #pragma unroll
        for (int r = 0; r < 4; r++) {
          int row = m0 + wm*(MT*16) + mt*16 + quad*4 + r;
          int col = n0 + wn*64 + nt*16 + c16;
          size_t o = (size_t)row * N + col;
          C[o] = q0 * X1[o] + q1 * acc[mt][nt][r];
        }
  } else {
    u16* Hc = (u16*)Cv;
    const int hbase = (n0 >> 1) + wn*32;
    #pragma unroll
    for (int mt = 0; mt < MT; mt++)
      #pragma unroll
      for (int r = 0; r < 4; r++) {
        int row = m0 + wm*(MT*16) + mt*16 + quad*4 + r;
        #pragma unroll
        for (int pr = 0; pr < 2; pr++) {
          float g = acc[mt][2*pr][r], u = acc[mt][2*pr+1][r];
          float h = g / (1.f + __expf(-g)) * u;
          Hc[(size_t)row * HIDP + hbase + pr*16 + c16] = f2bf(h);
        }
      }
  }
}

// ---------------- V^T GEMM: VT[b*1024+c][n] = sum_k Fv_l^T[c][k] * xn_l[b,n][k] --------
// grid (16, 8, 6); z = (level<<1)|b; early-exit x-blocks beyond Nl/128.
__global__ __launch_bounds__(256) void vgemm_k(const u16* __restrict__ Wqkv, const u16* __restrict__ xn_all,
                                               u16* __restrict__ VTa) {
  const int z = blockIdx.z, level = z >> 1, b = z & 1;
  const int Nl = 2048 >> level;
  if (blockIdx.x * 128 >= Nl) return;
  const int rowbase = (level==0) ? 0 : (level==1) ? 4096 : 6144;
  const size_t vtoff = (level==0) ? 0 : (level==1) ? 4194304 : 6291456;
  const u16* A  = Wqkv + (size_t)level*3072*1024 + (size_t)2048*1024;   // V rows of F_l^T
  const u16* BT = xn_all + (size_t)(rowbase + b*Nl) * 1024;
  u16* C = VTa + vtoff + (size_t)b*1024*Nl;
  const int K = 1024;

  __shared__ __align__(16) u16 As[128*32];
  __shared__ __align__(16) u16 Bs[128*32];
  const int tid = threadIdx.x;
  const int lane = tid & 63, wid = tid >> 6;
  const int quad = lane >> 4, c16 = lane & 15;
  const int m0 = blockIdx.y * 128, n0 = blockIdx.x * 128;
  const int wm = wid >> 1, wn = wid & 1;

  f32x4 acc[4][4];
  #pragma unroll
  for (int i = 0; i < 4; i++)
    #pragma unroll
    for (int j = 0; j < 4; j++) acc[i][j] = f32x4{0.f,0.f,0.f,0.f};

  const int srow = lane >> 2;
  const int schunk = lane & 3;
  for (int k0 = 0; k0 < K; k0 += 32) {
    #pragma unroll
    for (int t = 0; t < 2; t++) {
      int idx = wid*2 + t;
      int row = idx*16 + srow;
      int g = (schunk ^ ((row >> 1) & 3)) * 8;
      gload_lds16(A  + (size_t)(m0+row)*K + k0 + g, As + idx*512);
      gload_lds16(BT + (size_t)(n0+row)*K + k0 + g, Bs + idx*512);
    }
    __syncthreads();
    short8 af[4], bfr[4];
    #pragma unroll
    for (int mt = 0; mt < 4; mt++) {
      int ar = wm*64 + mt*16 + c16;
      af[mt]  = *(const short8*)(As + ar*32 + (quad ^ ((ar>>1)&3))*8);
    }
    #pragma unroll
    for (int nt = 0; nt < 4; nt++) {
      int br = wn*64 + nt*16 + c16;
      bfr[nt] = *(const short8*)(Bs + br*32 + (quad ^ ((br>>1)&3))*8);
    }
    #pragma unroll
    for (int mt = 0; mt < 4; mt++)
      #pragma unroll
      for (int nt = 0; nt < 4; nt++)
        acc[mt][nt] = __builtin_amdgcn_mfma_f32_16x16x32_bf16(af[mt], bfr[nt], acc[mt][nt], 0, 0, 0);
    __syncthreads();
  }
  #pragma unroll
  for (int mt = 0; mt < 4; mt++)
    #pragma unroll
    for (int nt = 0; nt < 4; nt++)
      #pragma unroll
      for (int r = 0; r < 4; r++) {
        int row = m0 + wm*64 + mt*16 + quad*4 + r;
        int col = n0 + wn*64 + nt*16 + c16;
        C[(size_t)row * Nl + col] = f2bf(acc[mt][nt][r]);
      }
}

// ---------------- MFMA flash attention, all levels merged, no-max online softmax ----
// QKVg rows now [b*Nl+n][2048]: Q at h*64, K at 1024+h*64.
__global__ __launch_bounds__(256) void flash_k(const u16* __restrict__ QKVg,
                                               const u16* __restrict__ VTg,
                                               u16* __restrict__ Og) {
  __shared__ __align__(16) u16 Kt[2][64*64];
  __shared__ __align__(16) u16 Vt[2][64*64];
  __shared__ __align__(16) u16 Ps[4][32*68];
  const int tid = threadIdx.x, lane = tid & 63, wid = tid >> 6;
  const int quad = lane >> 4, c16 = lane & 15;
  const int id = blockIdx.x;
  int qt, bh, Nl, rowbase; size_t vtoff;
  if (id < 512)      { qt = 15 - (id >> 5);            bh = id & 31;  Nl = 2048; rowbase = 0;    vtoff = 0; }
  else if (id < 768) { int t2 = id - 512; qt = 7 - (t2 >> 5); bh = t2 & 31; Nl = 1024; rowbase = 4096; vtoff = 4194304; }
  else               { int t2 = id - 768; qt = 3 - (t2 >> 5); bh = t2 & 31; Nl = 512;  rowbase = 6144; vtoff = 6291456; }
  const int b = bh >> 4, h = bh & 15;
  const u16* QK = QKVg + ((size_t)(rowbase + b*Nl)) * 2048 + h*64;
  u16* Ow = Og + ((size_t)(rowbase + b*Nl)) * 1024 + h*64;
  const u16* VT = VTg + vtoff + ((size_t)b*1024 + h*64) * (size_t)Nl;

  const int q0r = qt*128 + wid*32;
  short8 bq[2][2];
  #pragma unroll
  for (int qh = 0; qh < 2; qh++) {
    const u16* qp = QK + (size_t)(q0r + qh*16 + c16)*2048 + quad*8;
    bq[qh][0] = *(const short8*)qp;
    bq[qh][1] = *(const short8*)(qp + 32);
  }
  const int si0 = wid*2, si1 = si0 + 1;
  const int sr0 = si0*8 + (lane>>3), sr1 = si1*8 + (lane>>3);
  const int sg  = ((lane&7) ^ (lane>>3)) * 8;
  const u16* Ks0 = QK + 1024 + (size_t)sr0*2048 + sg;
  const u16* Ks1 = QK + 1024 + (size_t)sr1*2048 + sg;
  const u16* Vs0 = VT + (size_t)sr0*Nl + sg;
  const u16* Vs1 = VT + (size_t)sr1*Nl + sg;

  f32x4 oacc[2][4];
  f32x4 lacc[2];
  #pragma unroll
  for (int qh = 0; qh < 2; qh++) {
    lacc[qh] = f32x4{0.f,0.f,0.f,0.f};
    #pragma unroll
    for (int nt = 0; nt < 4; nt++) oacc[qh][nt] = f32x4{0.f,0.f,0.f,0.f};
  }

  auto stage = [&](int kt, int p) {
    const size_t ko = (size_t)kt * 64;
    gload_lds16(Ks0 + ko*2048, &Kt[p][si0*512]);
    gload_lds16(Ks1 + ko*2048, &Kt[p][si1*512]);
    gload_lds16(Vs0 + ko,      &Vt[p][si0*512]);
    gload_lds16(Vs1 + ko,      &Vt[p][si1*512]);
  };
  const int kmax_w = 2*qt + (wid >> 1);
  const int ktot   = 2*qt + 2;
  stage(0, 0);

  for (int kt = 0; kt < ktot; kt++) {
    const int p = kt & 1;
    __syncthreads();
    if (kt + 1 < ktot) stage(kt+1, p^1);
    if (kt > kmax_w) continue;

    f32x4 st[2][4];
    #pragma unroll
    for (int nt = 0; nt < 4; nt++) {
      int key = nt*16 + c16, x = key & 7;
      short8 a0 = *(const short8*)(&Kt[p][key*64 + ((quad    ) ^ x)*8]);
      short8 a1 = *(const short8*)(&Kt[p][key*64 + ((quad + 4) ^ x)*8]);
      #pragma unroll
      for (int qh = 0; qh < 2; qh++) {
        f32x4 s = f32x4{0.f,0.f,0.f,0.f};
        s = __builtin_amdgcn_mfma_f32_16x16x32_bf16(a0, bq[qh][0], s, 0, 0, 0);
        s = __builtin_amdgcn_mfma_f32_16x16x32_bf16(a1, bq[qh][1], s, 0, 0, 0);
        st[qh][nt] = s;
      }
    }
    if (kt >= 2*qt) {
      const int kb = kt*64;
      #pragma unroll
      for (int qh = 0; qh < 2; qh++) {
        const int qr = q0r + qh*16 + c16;
        #pragma unroll
        for (int nt = 0; nt < 4; nt++) {
          #pragma unroll
          for (int r = 0; r < 4; r++) {
            float e = __builtin_amdgcn_exp2f(st[qh][nt][r]);
            st[qh][nt][r] = (kb + nt*16 + quad*4 + r <= qr) ? e : 0.f;
          }
          lacc[qh] += st[qh][nt];
        }
      }
    } else {
      #pragma unroll
      for (int qh = 0; qh < 2; qh++)
        #pragma unroll
        for (int nt = 0; nt < 4; nt++) {
          #pragma unroll
          for (int r = 0; r < 4; r++) st[qh][nt][r] = __builtin_amdgcn_exp2f(st[qh][nt][r]);
          lacc[qh] += st[qh][nt];
        }
    }
    #pragma unroll
    for (int qh = 0; qh < 2; qh++) {
      const int prow = qh*16 + c16;
      #pragma unroll
      for (int nt = 0; nt < 4; nt++) {
        uint2 pk;
        pk.x = pkbf(st[qh][nt][0], st[qh][nt][1]);
        pk.y = pkbf(st[qh][nt][2], st[qh][nt][3]);
        *(uint2*)(&Ps[wid][prow*68 + nt*16 + quad*4]) = pk;
      }
    }
    short8 bp[2][2];
    #pragma unroll
    for (int qh = 0; qh < 2; qh++) {
      bp[qh][0] = *(const short8*)(&Ps[wid][(qh*16 + c16)*68 +      quad*8]);
      bp[qh][1] = *(const short8*)(&Ps[wid][(qh*16 + c16)*68 + 32 + quad*8]);
    }
    #pragma unroll
    for (int nt = 0; nt < 4; nt++) {
      int dh = nt*16 + c16, x = dh & 7;
      short8 a0 = *(const short8*)(&Vt[p][dh*64 + ((quad    ) ^ x)*8]);
      short8 a1 = *(const short8*)(&Vt[p][dh*64 + ((quad + 4) ^ x)*8]);
      #pragma unroll
      for (int qh = 0; qh < 2; qh++) {
        oacc[qh][nt] = __builtin_amdgcn_mfma_f32_16x16x32_bf16(a0, bp[qh][0], oacc[qh][nt], 0, 0, 0);
        oacc[qh][nt] = __builtin_amdgcn_mfma_f32_16x16x32_bf16(a1, bp[qh][1], oacc[qh][nt], 0, 0, 0);
      }
    }
  }
  #pragma unroll
  for (int qh = 0; qh < 2; qh++) {
    float ls = lacc[qh][0] + lacc[qh][1] + lacc[qh][2] + lacc[qh][3];
    ls += __shfl_xor(ls, 16);
    ls += __shfl_xor(ls, 32);
    const float rl = 1.f / ls;
    #pragma unroll
    for (int nt = 0; nt < 4; nt++) {
      uint2 o;
      o.x = pkbf(oacc[qh][nt][0]*rl, oacc[qh][nt][1]*rl);
      o.y = pkbf(oacc[qh][nt][2]*rl, oacc[qh][nt][3]*rl);
      *(uint2*)(Ow + (size_t)(q0r + qh*16 + c16)*1024 + nt*16 + quad*4) = o;
    }
  }
}

// ---------------- Gram matrix + (last block) Nash head + Sinkhorns ----------------
__global__ __launch_bounds__(256) void gramhead_k(const u16* __restrict__ Y0, const u16* __restrict__ Y1,
                                                  const u16* __restrict__ Y2, float* __restrict__ SC,
                                                  const float* __restrict__ agg, const float* __restrict__ mA,
                                                  const float* __restrict__ mF, float* __restrict__ aux_out) {
  float a[6] = {0,0,0,0,0,0};
  const int total4 = CNT/4;
  for (int i = blockIdx.x*256 + threadIdx.x; i < total4; i += gridDim.x*256) {
    int d4 = i & 255; int n = (i >> 8) & (N_-1); int b = i >> 19;
    u16x4 y0v = *(const u16x4*)(Y0 + (size_t)i*4);
    u16x4 y1v = *(const u16x4*)(Y1 + (((size_t)(b*1024 + (n>>1))) << 10) + d4*4);
    u16x4 y2v = *(const u16x4*)(Y2 + (((size_t)(b*512  + (n>>2))) << 10) + d4*4);
    #pragma unroll
    for (int t = 0; t < 4; t++) {
      float y0 = bf2f(y0v[t]), y1 = bf2f(y1v[t]), y2 = bf2f(y2v[t]);
      a[0] += y0*y0; a[1] += y0*y1; a[2] += y0*y2;
      a[3] += y1*y1; a[4] += y1*y2; a[5] += y2*y2;
    }
  }
  __shared__ float red[4][6];
  const int lane = threadIdx.x & 63, wid = threadIdx.x >> 6;
  #pragma unroll
  for (int t = 0; t < 6; t++) {
    float v = a[t];
    v += __shfl_xor(v, 1);  v += __shfl_xor(v, 2);  v += __shfl_xor(v, 4);
    v += __shfl_xor(v, 8);  v += __shfl_xor(v, 16); v += __shfl_xor(v, 32);
    a[t] = v;
  }
  if (lane == 0)
    #pragma unroll
    for (int t = 0; t < 6; t++) red[wid][t] = a[t];
  __syncthreads();
  if (threadIdx.x != 0) return;
  #pragma unroll
  for (int t = 0; t < 6; t++)
    atomicAdd(&SC[t], red[0][t] + red[1][t] + red[2][t] + red[3][t]);
  __threadfence();
  unsigned int* cnt = (unsigned int*)(SC + 32);
  unsigned int old = atomicAdd(cnt, 1u);
  if (old != gridDim.x - 1) return;
  __threadfence();
  // ---- last block: Nash head + Sinkhorns ----
  float G[6];
  for (int t = 0; t < 6; t++) G[t] = atomicAdd(&SC[t], 0.f);
  const int gi[3][3] = {{0,1,2},{1,3,4},{2,4,5}};
  float ag[3] = {agg[0], agg[1], agg[2]};
  float w[3];
  {
    float m = fmaxf(ag[0], fmaxf(ag[1], ag[2])); float s = 0.f;
    for (int l = 0; l < 3; l++) { w[l] = expf(ag[l]-m); s += w[l]; }
    for (int l = 0; l < 3; l++) w[l] /= s;
  }
  const float inv = 1.f / (float)CNT;
  for (int it = 0; it < 3; it++) {
    float q = 0.f;
    for (int l = 0; l < 3; l++) for (int m2 = 0; m2 < 3; m2++) q += w[l]*w[m2]*G[gi[l][m2]];
    float z[3];
    for (int l = 0; l < 3; l++) {
      float dot = w[0]*G[gi[l][0]] + w[1]*G[gi[l][1]] + w[2]*G[gi[l][2]];
      z[l] = ag[l] - (G[gi[l][l]] - 2.f*dot + q) * inv;
    }
    float m = fmaxf(z[0], fmaxf(z[1], z[2])); float s = 0.f;
    for (int l = 0; l < 3; l++) { w[l] = expf(z[l]-m); s += w[l]; }
    for (int l = 0; l < 3; l++) w[l] /= s;
  }
  SC[6] = w[0]; SC[7] = w[1]; SC[8] = w[2];
  aux_out[0] = w[0]*logf(w[0]*3.f + 1e-9f) + w[1]*logf(w[1]*3.f + 1e-9f) + w[2]*logf(w[2]*3.f + 1e-9f);
  for (int which = 0; which < 2; which++) {
    const float* Lg = which ? mF : mA;
    float M0 = expf(Lg[0]), M1 = expf(Lg[1]), M2 = expf(Lg[2]), M3 = expf(Lg[3]);
    for (int i2 = 0; i2 < 10; i2++) {
      float r0 = M0+M1, r1 = M2+M3; M0 /= r0; M1 /= r0; M2 /= r1; M3 /= r1;
      float c0 = M0+M2, c1 = M1+M3; M0 /= c0; M2 /= c0; M1 /= c1; M3 /= c1;
    }
    SC[9 + which*2] = M0; SC[10 + which*2] = M1;
  }
}

// ---------------- fused mix1 + FFN RMSNorm: one row per block ----------------
__global__ __launch_bounds__(256) void mixrms_k(const float* __restrict__ x, const u16* __restrict__ Y0,
                                                const u16* __restrict__ Y1, const u16* __restrict__ Y2,
                                                const float* __restrict__ SC, const float* __restrict__ w2,
                                                float* __restrict__ x1, u16* __restrict__ xn2) {
  const float w0 = SC[6], w1 = SC[7], ww2 = SC[8], p0 = SC[9], p1 = SC[10];
  const int i = blockIdx.x;
  const int b = i >> 11, n = i & 2047;
  const float* xr = x + (size_t)i * D_;
  const u16* y0 = Y0 + (size_t)i * D_;
  const u16* y1 = Y1 + (size_t)(b*1024 + (n>>1)) * D_;
  const u16* y2 = Y2 + (size_t)(b*512  + (n>>2)) * D_;
  float xv[4], wv[4];
  float ss = 0.f;
  #pragma unroll
  for (int t = 0; t < 4; t++) {
    int c = threadIdx.x + t*256;
    float v = p0*xr[c] + p1*(w0*bf2f(y0[c]) + w1*bf2f(y1[c]) + ww2*bf2f(y2[c]));
    xv[t] = v; wv[t] = w2[c]; ss += v*v;
    x1[(size_t)i*D_ + c] = v;
  }
  #pragma unroll
  for (int o = 1; o < 64; o <<= 1) ss += __shfl_xor(ss, o);
  __shared__ float red[4];
  if ((threadIdx.x & 63) == 0) red[threadIdx.x >> 6] = ss;
  __syncthreads();
  float sc = rsqrtf((red[0]+red[1]+red[2]+red[3]) * (1.f/D_) + 1e-6f);
  #pragma unroll
  for (int t = 0; t < 4; t++) {
    int c = threadIdx.x + t*256;
    xn2[(size_t)i*D_ + c] = f2bf(xv[t]*wv[t]*sc);
  }
}

// ================================ host launcher ================================
extern "C" void kernel_launch(void* const* d_in, const int* in_sizes, int n_in,
                              void* d_out, int out_size, void* d_ws, size_t ws_size,
                              hipStream_t stream) {
  (void)in_sizes; (void)n_in; (void)out_size; (void)ws_size;
  const float* x    = (const float*)d_in[0];
  const float* nw1  = (const float*)d_in[1];
  const float* nw2  = (const float*)d_in[2];
  const float* Wdec = (const float*)d_in[3];
  const float* Wq   = (const float*)d_in[4];
  const float* Wk   = (const float*)d_in[5];
  const float* Wv   = (const float*)d_in[6];
  const float* Wo   = (const float*)d_in[7];
  const float* agg  = (const float*)d_in[8];
  const float* Wg   = (const float*)d_in[9];
  const float* Wu   = (const float*)d_in[10];
  const float* Wdn  = (const float*)d_in[11];
  const float* mA   = (const float*)d_in[12];
  const float* mF   = (const float*)d_in[13];
  float* out = (float*)d_out;

  char* ws = (char*)d_ws;
  size_t off = 0;
  auto take = [&](size_t b) { size_t r = off; off += (b + 255) & ~(size_t)255; return r; };

  u16* A_wp  = (u16*)(ws + take((size_t)9216*1024*2));
  u16* WdecB = (u16*)(ws + take((size_t)3*1024*1024*2));
  u16* Wqkv  = (u16*)(ws + take((size_t)9216*1024*2));
  u16* BTgu  = (u16*)(ws + take((size_t)5632*1024*2));   // gate/up 16-col interleaved
  u16* WdnT  = (u16*)(ws + take((size_t)HIDP*1024*2));
  u16* WoT   = (u16*)(ws + take((size_t)1024*1024*2));
  u16* xn_all = (u16*)(ws + take((size_t)7168*1024*2));
  float* x1  = (float*)(ws + take((size_t)CNT*4));
  float* SCb = (float*)(ws + take(256));
  char*  big = ws + take(88080384);
  // attention phase
  u16*   QKV   = (u16*)big;                              // [7168, 2048] bf16 (Q|K)
  u16*   VTa   = (u16*)(big + 29360128);                 // per-level [b][1024][Nl]
  u16*   Ob    = (u16*)(big + 44040192);                 // [7168, 1024] bf16
  u16*   YC    = (u16*)(big + 58720256);                 // [7168, 1024] bf16
  // FFN phase alias (attention working set dead by then; YC region untouched)
  u16*   hbuf  = (u16*)big;                              // [4096, 2816] bf16

  dim3 blk(256);
  const int BIG = 1 << 30;

  // ---- 1: all weight prep in one launch (+ SCb/ticket zero) ----
  wprep_k<<<21760, blk, 0, stream>>>(Wdec, Wq, Wk, Wv, Wo, Wg, Wu, Wdn,
                                     A_wp, WdecB, WoT, BTgu, WdnT, SCb);
  // ---- 2: fused QKV weights: F_l^T = [Wq|Wk|Wv]_l^T x Wdec_l^T ----
  gemm_t<4,1><<<dim3(8, 72), blk, 0, stream>>>(A_wp, WdecB, Wqkv, nullptr, nullptr,
                                               1024, 1024, 24, 48, 1024u*1024u);
  // ---- 3: attention RMSNorm + both pools ----
  rmsA_k<<<1024, blk, 0, stream>>>(x, nw1, xn_all,
                                   xn_all + (size_t)4096*1024, xn_all + (size_t)6144*1024);
  // ---- 4: QK GEMM (per-level weight select), stride-2048 output ----
  gemm_t<4,1><<<dim3(16, 56), blk, 0, stream>>>(xn_all, Wqkv, QKV, nullptr, nullptr,
                                                2048, 1024, 32, 48, 3072u*1024u);
  // ---- 5: V^T GEMM (replaces V-projection + transpose) ----
  vgemm_k<<<dim3(16, 8, 6), blk, 0, stream>>>(Wqkv, xn_all, VTa);
  // ---- 6: flash attention (all levels) ----
  flash_k<<<896, blk, 0, stream>>>(QKV, VTa, Ob);
  // ---- 7: output projection -> YC (bf16) ----
  gemm_t<2,1><<<dim3(8, 112), blk, 0, stream>>>(Ob, WoT, YC, nullptr, nullptr,
                                                1024, 1024, BIG, BIG, 0u);
  // ---- 8: Gram + Nash head + Sinkhorns (last-block) ----
  u16* YC1 = YC + (size_t)4096*1024;
  u16* YC2 = YC + (size_t)6144*1024;
  gramhead_k<<<1024, blk, 0, stream>>>(YC, YC1, YC2, SCb, agg, mA, mF, out + CNT);
  // ---- 9: mix1 + FFN RMSNorm fused ----
  mixrms_k<<<4096, blk, 0, stream>>>(x, YC, YC1, YC2, SCb, nw2, x1, xn_all);
  // ---- 10: gate/up GEMM with fused silu*mul epilogue ----
  gemm_t<4,3><<<dim3(44, 32), blk, 0, stream>>>(xn_all, BTgu, hbuf, nullptr, nullptr,
                                                5632, 1024, BIG, BIG, 0u);
  // ---- 11: down GEMM with fused final residual mix ----
  gemm_t<2,2><<<dim3(8, 64), blk, 0, stream>>>(hbuf, WdnT, out, x1, SCb,
                                               1024, HIDP, BIG, BIG, 0u);
}

// Round 7
// 507.545 us; speedup vs baseline: 1.1655x; 1.1655x over previous
//
#include <hip/hip_runtime.h>
#include <stdint.h>

// MAHA decoder block, MI355X/gfx950. Round 7: revert fence-heavy gramhead (R6 regression),
// keep V^T-as-GEMM + pool fusion; compact vgemm grid.
// B=2, N=2048, D=1024, H=16(dh=64), L=3, R=2, HID=2734(->2816), fp32 I/O.

#define B_   2
#define N_   2048
#define D_   1024
#define H_   16
#define DH_  64
#define HID_ 2734
#define HIDP 2816
#define CNT  (B_*N_*D_)   // 4194304
#define LOG2E 1.4426950408889634f

typedef unsigned short u16;
typedef __attribute__((ext_vector_type(8))) short short8;
typedef __attribute__((ext_vector_type(4))) float f32x4;
typedef __attribute__((ext_vector_type(4))) uint16_t u16x4;

__device__ __forceinline__ u16 f2bf(float f) {
  uint32_t u = __builtin_bit_cast(uint32_t, f);
  u += 0x7fffu + ((u >> 16) & 1u);          // RNE
  return (u16)(u >> 16);
}
__device__ __forceinline__ float bf2f(u16 h) {
  uint32_t u = ((uint32_t)h) << 16;
  return __builtin_bit_cast(float, u);
}
__device__ __forceinline__ uint32_t pkbf(float a, float b) {
  return (uint32_t)f2bf(a) | ((uint32_t)f2bf(b) << 16);
}
__device__ __forceinline__ void gload_lds16(const void* g, void* l) {
  __builtin_amdgcn_global_load_lds(
      (const __attribute__((address_space(1))) uint32_t*)g,
      (__attribute__((address_space(3))) uint32_t*)l, 16, 0, 0);
}

// ============ batched weight prep: all fp32->bf16 transposes + Wdec convert + SC zero ====
__global__ __launch_bounds__(256) void wprep_k(const float* __restrict__ Wdec, const float* __restrict__ Wq,
                                               const float* __restrict__ Wk, const float* __restrict__ Wv,
                                               const float* __restrict__ Wo, const float* __restrict__ Wg,
                                               const float* __restrict__ Wu, const float* __restrict__ Wdn,
                                               u16* __restrict__ A_wp, u16* __restrict__ WdecB,
                                               u16* __restrict__ WoT, u16* __restrict__ BTgu,
                                               u16* __restrict__ WdnT, float* __restrict__ SCb) {
  const int bid = blockIdx.x;
  if (bid >= 18688) {
    if (bid == 18688 && threadIdx.x < 64) SCb[threadIdx.x] = 0.f;
    int i = (bid - 18688)*1024 + threadIdx.x*4;
    float4 v = *(const float4*)(Wdec + i);
    u16x4 o; o[0]=f2bf(v.x); o[1]=f2bf(v.y); o[2]=f2bf(v.z); o[3]=f2bf(v.w);
    *(u16x4*)(WdecB + i) = o;
    return;
  }
  const float* src; u16* dst; int K, N, KP; float scale; int imode; int bx, by;
  if (bid < 9216) {
    int j = bid >> 10, t = bid & 1023; bx = t & 31; by = t >> 5;
    int l = j / 3, which = j - l*3;
    src = which==0 ? Wq + (size_t)l*1048576 : which==1 ? Wk + (size_t)l*1048576 : Wv;
    dst = A_wp + (size_t)(l*3072 + which*1024)*1024;
    K = 1024; N = 1024; KP = 1024; scale = (which==0) ? 0.125f*LOG2E : 1.f; imode = 0;
  } else if (bid < 10240) {
    int t = bid - 9216; bx = t & 31; by = t >> 5;
    src = Wo; dst = WoT; K=1024; N=1024; KP=1024; scale=1.f; imode=0;
  } else if (bid < 13056) {
    int t = bid - 10240; bx = t % 88; by = t / 88;
    src = Wg; dst = BTgu; K=1024; N=HID_; KP=1024; scale=1.f; imode=1;
  } else if (bid < 15872) {
    int t = bid - 13056; bx = t % 88; by = t / 88;
    src = Wu; dst = BTgu; K=1024; N=HID_; KP=1024; scale=1.f; imode=2;
  } else {
    int t = bid - 15872; bx = t & 31; by = t >> 5;
    src = Wdn; dst = WdnT; K=HID_; N=1024; KP=HIDP; scale=1.f; imode=0;
  }
  __shared__ float tt[32][33];
  const int tx = threadIdx.x & 31, ty = threadIdx.x >> 5;
  const int nb = bx*32, kb = by*32;
  #pragma unroll
  for (int i = 0; i < 4; i++) {
    int k = kb + ty + i*8, n = nb + tx;
    tt[ty + i*8][tx] = (k < K && n < N) ? src[(size_t)k * N + n] * scale : 0.f;
  }
  __syncthreads();
  #pragma unroll
  for (int i = 0; i < 4; i++) {
    int n = nb + ty + i*8, k = kb + tx;
    int r;
    if (imode == 0) r = n;
    else if (imode == 1) r = ((n>>4)<<5) + (n&15);
    else r = ((n>>4)<<5) + 16 + (n&15);
    dst[(size_t)r * KP + k] = f2bf(tt[tx][ty + i*8]);
  }
}

// ---------------- attention RMSNorm: 4 rows per block + both pooled levels (fp32) -------
__global__ __launch_bounds__(256) void rmsA_k(const float* __restrict__ x, const float* __restrict__ w,
                                              u16* __restrict__ xn, u16* __restrict__ xp1,
                                              u16* __restrict__ xp2) {
  const int j = blockIdx.x;                       // rows 4j..4j+3
  const float* xr = x + (size_t)(4*j) * D_;
  float a[4][4], wv[4];
  float ss[4] = {0.f, 0.f, 0.f, 0.f};
  #pragma unroll
  for (int i = 0; i < 4; i++) {
    int c = threadIdx.x + i*256;
    wv[i] = w[c];
    #pragma unroll
    for (int r = 0; r < 4; r++) { float v = xr[(size_t)r*D_ + c]; a[r][i] = v; ss[r] += v*v; }
  }
  #pragma unroll
  for (int o = 1; o < 64; o <<= 1) {
    #pragma unroll
    for (int r = 0; r < 4; r++) ss[r] += __shfl_xor(ss[r], o);
  }
  __shared__ float red[4][4];
  if ((threadIdx.x & 63) == 0) {
    #pragma unroll
    for (int r = 0; r < 4; r++) red[threadIdx.x >> 6][r] = ss[r];
  }
  __syncthreads();
  float sc[4];
  #pragma unroll
  for (int r = 0; r < 4; r++)
    sc[r] = rsqrtf((red[0][r]+red[1][r]+red[2][r]+red[3][r]) * (1.f/D_) + 1e-6f);
  #pragma unroll
  for (int i = 0; i < 4; i++) {
    int c = threadIdx.x + i*256;
    float v0 = a[0][i]*wv[i]*sc[0], v1 = a[1][i]*wv[i]*sc[1];
    float v2 = a[2][i]*wv[i]*sc[2], v3 = a[3][i]*wv[i]*sc[3];
    xn[(size_t)(4*j  )*D_ + c] = f2bf(v0);
    xn[(size_t)(4*j+1)*D_ + c] = f2bf(v1);
    xn[(size_t)(4*j+2)*D_ + c] = f2bf(v2);
    xn[(size_t)(4*j+3)*D_ + c] = f2bf(v3);
    xp1[(size_t)(2*j  )*D_ + c] = f2bf(0.5f*(v0+v1));
    xp1[(size_t)(2*j+1)*D_ + c] = f2bf(0.5f*(v2+v3));
    xp2[(size_t)j*D_ + c] = f2bf(0.25f*(v0+v1+v2+v3));
  }
}

// ---------------- MFMA GEMM, C = A[M,K] * BT[N,K]^T; block = MT*32 x 128 ----------------
// MODE 1: bf16 store. MODE 2: fp32 out = SCp[11]*X1 + SCp[12]*acc. MODE 3: silu(gate)*up
template<int MT, int MODE>
__global__ __launch_bounds__(256) void gemm_t(const u16* __restrict__ A, const u16* __restrict__ BT,
                                              void* __restrict__ Cv, const float* __restrict__ X1,
                                              const float* __restrict__ SCp,
                                              int N, int K, int t1, int t2, unsigned int bt_stride) {
  __shared__ __align__(16) u16 As[MT*32*32];
  __shared__ __align__(16) u16 Bs[128*32];
  const int tid = threadIdx.x;
  const int lane = tid & 63, wid = tid >> 6;
  const int quad = lane >> 4, c16 = lane & 15;
  const int y = blockIdx.y;
  const int m0 = y * (MT*32), n0 = blockIdx.x * 128;
  const int wm = wid >> 1, wn = wid & 1;
  const int level = (y >= t2) ? 2 : ((y >= t1) ? 1 : 0);
  BT += (size_t)level * bt_stride;

  f32x4 acc[MT][4];
  #pragma unroll
  for (int i = 0; i < MT; i++)
    #pragma unroll
    for (int j = 0; j < 4; j++) acc[i][j] = f32x4{0.f,0.f,0.f,0.f};

  const int srow = lane >> 2;
  const int schunk = lane & 3;
  for (int k0 = 0; k0 < K; k0 += 32) {
    #pragma unroll
    for (int t = 0; t < MT/2; t++) {
      int idx = wid*(MT/2) + t;
      int row = idx*16 + srow;
      int g = (schunk ^ ((row >> 1) & 3)) * 8;
      gload_lds16(A + (size_t)(m0+row)*K + k0 + g, As + idx*512);
    }
    #pragma unroll
    for (int t = 0; t < 2; t++) {
      int idx = wid*2 + t;
      int row = idx*16 + srow;
      int g = (schunk ^ ((row >> 1) & 3)) * 8;
      gload_lds16(BT + (size_t)(n0+row)*K + k0 + g, Bs + idx*512);
    }
    __syncthreads();
    short8 af[MT], bfr[4];
    #pragma unroll
    for (int mt = 0; mt < MT; mt++) {
      int ar = wm*(MT*16) + mt*16 + c16;
      af[mt]  = *(const short8*)(As + ar*32 + (quad ^ ((ar>>1)&3))*8);
    }
    #pragma unroll
    for (int nt = 0; nt < 4; nt++) {
      int br = wn*64 + nt*16 + c16;
      bfr[nt] = *(const short8*)(Bs + br*32 + (quad ^ ((br>>1)&3))*8);
    }
    #pragma unroll
    for (int mt = 0; mt < MT; mt++)
      #pragma unroll
      for (int nt = 0; nt < 4; nt++)
        acc[mt][nt] = __builtin_amdgcn_mfma_f32_16x16x32_bf16(af[mt], bfr[nt], acc[mt][nt], 0, 0, 0);
    __syncthreads();
  }
  if (MODE == 1) {
    u16* C = (u16*)Cv;
    #pragma unroll
    for (int mt = 0; mt < MT; mt++)
      #pragma unroll
      for (int nt = 0; nt < 4; nt++)
        #pragma unroll
        for (int r = 0; r < 4; r++) {
          int row = m0 + wm*(MT*16) + mt*16 + quad*4 + r;
          int col = n0 + wn*64 + nt*16 + c16;
          C[(size_t)row * N + col] = f2bf(acc[mt][nt][r]);
        }
  } else if (MODE == 2) {
    float* C = (float*)Cv;
    const float q0 = SCp[11], q1 = SCp[12];
    #pragma unroll
    for (int mt = 0; mt < MT; mt++)
      #pragma unroll
      for (int nt = 0; nt < 4; nt++)
        #pragma unroll
        for (int r = 0; r < 4; r++) {
          int row = m0 + wm*(MT*16) + mt*16 + quad*4 + r;
          int col = n0 + wn*64 + nt*16 + c16;
          size_t o = (size_t)row * N + col;
          C[o] = q0 * X1[o] + q1 * acc[mt][nt][r];
        }
  } else {
    u16* Hc = (u16*)Cv;
    const int hbase = (n0 >> 1) + wn*32;
    #pragma unroll
    for (int mt = 0; mt < MT; mt++)
      #pragma unroll
      for (int r = 0; r < 4; r++) {
        int row = m0 + wm*(MT*16) + mt*16 + quad*4 + r;
        #pragma unroll
        for (int pr = 0; pr < 2; pr++) {
          float g = acc[mt][2*pr][r], u = acc[mt][2*pr+1][r];
          float h = g / (1.f + __expf(-g)) * u;
          Hc[(size_t)row * HIDP + hbase + pr*16 + c16] = f2bf(h);
        }
      }
  }
}

// ---------------- V^T GEMM: VT[b*1024+c][n] = sum_k Fv_l^T[c][k] * xn_l[b,n][k] --------
// compact 448-block grid: L0 256 (2b x 8m x 16n) | L1 128 (2x8x8) | L2 64 (2x8x4)
__global__ __launch_bounds__(256) void vgemm_k(const u16* __restrict__ Wqkv, const u16* __restrict__ xn_all,
                                               u16* __restrict__ VTa) {
  const int id = blockIdx.x;
  int level, b, my, nx;
  if (id < 256)      { level = 0; int r2 = id;        b = r2 >> 7; int t = r2 & 127; my = t >> 4; nx = t & 15; }
  else if (id < 384) { level = 1; int r2 = id - 256;  b = r2 >> 6; int t = r2 & 63;  my = t >> 3; nx = t & 7; }
  else               { level = 2; int r2 = id - 384;  b = r2 >> 5; int t = r2 & 31;  my = t >> 2; nx = t & 3; }
  const int Nl = 2048 >> level;
  const int rowbase = (level==0) ? 0 : (level==1) ? 4096 : 6144;
  const size_t vtoff = (level==0) ? 0 : (level==1) ? 4194304 : 6291456;
  const u16* A  = Wqkv + (size_t)level*3072*1024 + (size_t)2048*1024;   // V rows of F_l^T
  const u16* BT = xn_all + (size_t)(rowbase + b*Nl) * 1024;
  u16* C = VTa + vtoff + (size_t)b*1024*Nl;
  const int K = 1024;

  __shared__ __align__(16) u16 As[128*32];
  __shared__ __align__(16) u16 Bs[128*32];
  const int tid = threadIdx.x;
  const int lane = tid & 63, wid = tid >> 6;
  const int quad = lane >> 4, c16 = lane & 15;
  const int m0 = my * 128, n0 = nx * 128;
  const int wm = wid >> 1, wn = wid & 1;

  f32x4 acc[4][4];
  #pragma unroll
  for (int i = 0; i < 4; i++)
    #pragma unroll
    for (int j = 0; j < 4; j++) acc[i][j] = f32x4{0.f,0.f,0.f,0.f};

  const int srow = lane >> 2;
  const int schunk = lane & 3;
  for (int k0 = 0; k0 < K; k0 += 32) {
    #pragma unroll
    for (int t = 0; t < 2; t++) {
      int idx = wid*2 + t;
      int row = idx*16 + srow;
      int g = (schunk ^ ((row >> 1) & 3)) * 8;
      gload_lds16(A  + (size_t)(m0+row)*K + k0 + g, As + idx*512);
      gload_lds16(BT + (size_t)(n0+row)*K + k0 + g, Bs + idx*512);
    }
    __syncthreads();
    short8 af[4], bfr[4];
    #pragma unroll
    for (int mt = 0; mt < 4; mt++) {
      int ar = wm*64 + mt*16 + c16;
      af[mt]  = *(const short8*)(As + ar*32 + (quad ^ ((ar>>1)&3))*8);
    }
    #pragma unroll
    for (int nt = 0; nt < 4; nt++) {
      int br = wn*64 + nt*16 + c16;
      bfr[nt] = *(const short8*)(Bs + br*32 + (quad ^ ((br>>1)&3))*8);
    }
    #pragma unroll
    for (int mt = 0; mt < 4; mt++)
      #pragma unroll
      for (int nt = 0; nt < 4; nt++)
        acc[mt][nt] = __builtin_amdgcn_mfma_f32_16x16x32_bf16(af[mt], bfr[nt], acc[mt][nt], 0, 0, 0);
    __syncthreads();
  }
  #pragma unroll
  for (int mt = 0; mt < 4; mt++)
    #pragma unroll
    for (int nt = 0; nt < 4; nt++)
      #pragma unroll
      for (int r = 0; r < 4; r++) {
        int row = m0 + wm*64 + mt*16 + quad*4 + r;
        int col = n0 + wn*64 + nt*16 + c16;
        C[(size_t)row * Nl + col] = f2bf(acc[mt][nt][r]);
      }
}

// ---------------- MFMA flash attention, all levels merged, no-max online softmax ----
// QKVg rows [b*Nl+n][2048]: Q at h*64, K at 1024+h*64.
__global__ __launch_bounds__(256) void flash_k(const u16* __restrict__ QKVg,
                                               const u16* __restrict__ VTg,
                                               u16* __restrict__ Og) {
  __shared__ __align__(16) u16 Kt[2][64*64];
  __shared__ __align__(16) u16 Vt[2][64*64];
  __shared__ __align__(16) u16 Ps[4][32*68];
  const int tid = threadIdx.x, lane = tid & 63, wid = tid >> 6;
  const int quad = lane >> 4, c16 = lane & 15;
  const int id = blockIdx.x;
  int qt, bh, Nl, rowbase; size_t vtoff;
  if (id < 512)      { qt = 15 - (id >> 5);            bh = id & 31;  Nl = 2048; rowbase = 0;    vtoff = 0; }
  else if (id < 768) { int t2 = id - 512; qt = 7 - (t2 >> 5); bh = t2 & 31; Nl = 1024; rowbase = 4096; vtoff = 4194304; }
  else               { int t2 = id - 768; qt = 3 - (t2 >> 5); bh = t2 & 31; Nl = 512;  rowbase = 6144; vtoff = 6291456; }
  const int b = bh >> 4, h = bh & 15;
  const u16* QK = QKVg + ((size_t)(rowbase + b*Nl)) * 2048 + h*64;
  u16* Ow = Og + ((size_t)(rowbase + b*Nl)) * 1024 + h*64;
  const u16* VT = VTg + vtoff + ((size_t)b*1024 + h*64) * (size_t)Nl;

  const int q0r = qt*128 + wid*32;
  short8 bq[2][2];
  #pragma unroll
  for (int qh = 0; qh < 2; qh++) {
    const u16* qp = QK + (size_t)(q0r + qh*16 + c16)*2048 + quad*8;
    bq[qh][0] = *(const short8*)qp;
    bq[qh][1] = *(const short8*)(qp + 32);
  }
  const int si0 = wid*2, si1 = si0 + 1;
  const int sr0 = si0*8 + (lane>>3), sr1 = si1*8 + (lane>>3);
  const int sg  = ((lane&7) ^ (lane>>3)) * 8;
  const u16* Ks0 = QK + 1024 + (size_t)sr0*2048 + sg;
  const u16* Ks1 = QK + 1024 + (size_t)sr1*2048 + sg;
  const u16* Vs0 = VT + (size_t)sr0*Nl + sg;
  const u16* Vs1 = VT + (size_t)sr1*Nl + sg;

  f32x4 oacc[2][4];
  f32x4 lacc[2];
  #pragma unroll
  for (int qh = 0; qh < 2; qh++) {
    lacc[qh] = f32x4{0.f,0.f,0.f,0.f};
    #pragma unroll
    for (int nt = 0; nt < 4; nt++) oacc[qh][nt] = f32x4{0.f,0.f,0.f,0.f};
  }

  auto stage = [&](int kt, int p) {
    const size_t ko = (size_t)kt * 64;
    gload_lds16(Ks0 + ko*2048, &Kt[p][si0*512]);
    gload_lds16(Ks1 + ko*2048, &Kt[p][si1*512]);
    gload_lds16(Vs0 + ko,      &Vt[p][si0*512]);
    gload_lds16(Vs1 + ko,      &Vt[p][si1*512]);
  };
  const int kmax_w = 2*qt + (wid >> 1);
  const int ktot   = 2*qt + 2;
  stage(0, 0);

  for (int kt = 0; kt < ktot; kt++) {
    const int p = kt & 1;
    __syncthreads();
    if (kt + 1 < ktot) stage(kt+1, p^1);
    if (kt > kmax_w) continue;

    f32x4 st[2][4];
    #pragma unroll
    for (int nt = 0; nt < 4; nt++) {
      int key = nt*16 + c16, x = key & 7;
      short8 a0 = *(const short8*)(&Kt[p][key*64 + ((quad    ) ^ x)*8]);
      short8 a1 = *(const short8*)(&Kt[p][key*64 + ((quad + 4) ^ x)*8]);
      #pragma unroll
      for (int qh = 0; qh < 2; qh++) {
        f32x4 s = f32x4{0.f,0.f,0.f,0.f};
        s = __builtin_amdgcn_mfma_f32_16x16x32_bf16(a0, bq[qh][0], s, 0, 0, 0);
        s = __builtin_amdgcn_mfma_f32_16x16x32_bf16(a1, bq[qh][1], s, 0, 0, 0);
        st[qh][nt] = s;
      }
    }
    if (kt >= 2*qt) {
      const int kb = kt*64;
      #pragma unroll
      for (int qh = 0; qh < 2; qh++) {
        const int qr = q0r + qh*16 + c16;
        #pragma unroll
        for (int nt = 0; nt < 4; nt++) {
          #pragma unroll
          for (int r = 0; r < 4; r++) {
            float e = __builtin_amdgcn_exp2f(st[qh][nt][r]);
            st[qh][nt][r] = (kb + nt*16 + quad*4 + r <= qr) ? e : 0.f;
          }
          lacc[qh] += st[qh][nt];
        }
      }
    } else {
      #pragma unroll
      for (int qh = 0; qh < 2; qh++)
        #pragma unroll
        for (int nt = 0; nt < 4; nt++) {
          #pragma unroll
          for (int r = 0; r < 4; r++) st[qh][nt][r] = __builtin_amdgcn_exp2f(st[qh][nt][r]);
          lacc[qh] += st[qh][nt];
        }
    }
    #pragma unroll
    for (int qh = 0; qh < 2; qh++) {
      const int prow = qh*16 + c16;
      #pragma unroll
      for (int nt = 0; nt < 4; nt++) {
        uint2 pk;
        pk.x = pkbf(st[qh][nt][0], st[qh][nt][1]);
        pk.y = pkbf(st[qh][nt][2], st[qh][nt][3]);
        *(uint2*)(&Ps[wid][prow*68 + nt*16 + quad*4]) = pk;
      }
    }
    short8 bp[2][2];
    #pragma unroll
    for (int qh = 0; qh < 2; qh++) {
      bp[qh][0] = *(const short8*)(&Ps[wid][(qh*16 + c16)*68 +      quad*8]);
      bp[qh][1] = *(const short8*)(&Ps[wid][(qh*16 + c16)*68 + 32 + quad*8]);
    }
    #pragma unroll
    for (int nt = 0; nt < 4; nt++) {
      int dh = nt*16 + c16, x = dh & 7;
      short8 a0 = *(const short8*)(&Vt[p][dh*64 + ((quad    ) ^ x)*8]);
      short8 a1 = *(const short8*)(&Vt[p][dh*64 + ((quad + 4) ^ x)*8]);
      #pragma unroll
      for (int qh = 0; qh < 2; qh++) {
        oacc[qh][nt] = __builtin_amdgcn_mfma_f32_16x16x32_bf16(a0, bp[qh][0], oacc[qh][nt], 0, 0, 0);
        oacc[qh][nt] = __builtin_amdgcn_mfma_f32_16x16x32_bf16(a1, bp[qh][1], oacc[qh][nt], 0, 0, 0);
      }
    }
  }
  #pragma unroll
  for (int qh = 0; qh < 2; qh++) {
    float ls = lacc[qh][0] + lacc[qh][1] + lacc[qh][2] + lacc[qh][3];
    ls += __shfl_xor(ls, 16);
    ls += __shfl_xor(ls, 32);
    const float rl = 1.f / ls;
    #pragma unroll
    for (int nt = 0; nt < 4; nt++) {
      uint2 o;
      o.x = pkbf(oacc[qh][nt][0]*rl, oacc[qh][nt][1]*rl);
      o.y = pkbf(oacc[qh][nt][2]*rl, oacc[qh][nt][3]*rl);
      *(uint2*)(Ow + (size_t)(q0r + qh*16 + c16)*1024 + nt*16 + quad*4) = o;
    }
  }
}

// ---------------- Gram matrix over repeat map (bf16 Y), 4-wide, no fences ----------------
__global__ __launch_bounds__(256) void gram_k(const u16* __restrict__ Y0, const u16* __restrict__ Y1,
                                              const u16* __restrict__ Y2, float* __restrict__ G) {
  float a[6] = {0,0,0,0,0,0};
  const int total4 = CNT/4;
  for (int i = blockIdx.x*256 + threadIdx.x; i < total4; i += gridDim.x*256) {
    int d4 = i & 255; int n = (i >> 8) & (N_-1); int b = i >> 19;
    u16x4 y0v = *(const u16x4*)(Y0 + (size_t)i*4);
    u16x4 y1v = *(const u16x4*)(Y1 + (((size_t)(b*1024 + (n>>1))) << 10) + d4*4);
    u16x4 y2v = *(const u16x4*)(Y2 + (((size_t)(b*512  + (n>>2))) << 10) + d4*4);
    #pragma unroll
    for (int t = 0; t < 4; t++) {
      float y0 = bf2f(y0v[t]), y1 = bf2f(y1v[t]), y2 = bf2f(y2v[t]);
      a[0] += y0*y0; a[1] += y0*y1; a[2] += y0*y2;
      a[3] += y1*y1; a[4] += y1*y2; a[5] += y2*y2;
    }
  }
  __shared__ float red[4][6];
  const int lane = threadIdx.x & 63, wid = threadIdx.x >> 6;
  #pragma unroll
  for (int t = 0; t < 6; t++) {
    float v = a[t];
    v += __shfl_xor(v, 1);  v += __shfl_xor(v, 2);  v += __shfl_xor(v, 4);
    v += __shfl_xor(v, 8);  v += __shfl_xor(v, 16); v += __shfl_xor(v, 32);
    a[t] = v;
  }
  if (lane == 0)
    #pragma unroll
    for (int t = 0; t < 6; t++) red[wid][t] = a[t];
  __syncthreads();
  if (threadIdx.x < 6)
    atomicAdd(&G[threadIdx.x], red[0][threadIdx.x] + red[1][threadIdx.x] +
                               red[2][threadIdx.x] + red[3][threadIdx.x]);
}

// ---------------- Nash iterations + aux loss + both Sinkhorns (scalar) ----------------
__global__ void head_k(float* SC, const float* __restrict__ agg, const float* __restrict__ mA,
                       const float* __restrict__ mF, float* __restrict__ aux_out) {
  if (threadIdx.x != 0 || blockIdx.x != 0) return;
  float G[6];
  for (int t = 0; t < 6; t++) G[t] = SC[t];
  const int gi[3][3] = {{0,1,2},{1,3,4},{2,4,5}};
  float a[3] = {agg[0], agg[1], agg[2]};
  float w[3];
  {
    float m = fmaxf(a[0], fmaxf(a[1], a[2])); float s = 0.f;
    for (int l = 0; l < 3; l++) { w[l] = expf(a[l]-m); s += w[l]; }
    for (int l = 0; l < 3; l++) w[l] /= s;
  }
  const float inv = 1.f / (float)CNT;
  for (int it = 0; it < 3; it++) {
    float q = 0.f;
    for (int l = 0; l < 3; l++) for (int m2 = 0; m2 < 3; m2++) q += w[l]*w[m2]*G[gi[l][m2]];
    float z[3];
    for (int l = 0; l < 3; l++) {
      float dot = w[0]*G[gi[l][0]] + w[1]*G[gi[l][1]] + w[2]*G[gi[l][2]];
      z[l] = a[l] - (G[gi[l][l]] - 2.f*dot + q) * inv;
    }
    float m = fmaxf(z[0], fmaxf(z[1], z[2])); float s = 0.f;
    for (int l = 0; l < 3; l++) { w[l] = expf(z[l]-m); s += w[l]; }
    for (int l = 0; l < 3; l++) w[l] /= s;
  }
  SC[6] = w[0]; SC[7] = w[1]; SC[8] = w[2];
  aux_out[0] = w[0]*logf(w[0]*3.f + 1e-9f) + w[1]*logf(w[1]*3.f + 1e-9f) + w[2]*logf(w[2]*3.f + 1e-9f);
  for (int which = 0; which < 2; which++) {
    const float* Lg = which ? mF : mA;
    float M0 = expf(Lg[0]), M1 = expf(Lg[1]), M2 = expf(Lg[2]), M3 = expf(Lg[3]);
    for (int i2 = 0; i2 < 10; i2++) {
      float r0 = M0+M1, r1 = M2+M3; M0 /= r0; M1 /= r0; M2 /= r1; M3 /= r1;
      float c0 = M0+M2, c1 = M1+M3; M0 /= c0; M2 /= c0; M1 /= c1; M3 /= c1;
    }
    SC[9 + which*2] = M0; SC[10 + which*2] = M1;
  }
}

// ---------------- fused mix1 + FFN RMSNorm: one row per block ----------------
__global__ __launch_bounds__(256) void mixrms_k(const float* __restrict__ x, const u16* __restrict__ Y0,
                                                const u16* __restrict__ Y1, const u16* __restrict__ Y2,
                                                const float* __restrict__ SC, const float* __restrict__ w2,
                                                float* __restrict__ x1, u16* __restrict__ xn2) {
  const float w0 = SC[6], w1 = SC[7], ww2 = SC[8], p0 = SC[9], p1 = SC[10];
  const int i = blockIdx.x;
  const int b = i >> 11, n = i & 2047;
  const float* xr = x + (size_t)i * D_;
  const u16* y0 = Y0 + (size_t)i * D_;
  const u16* y1 = Y1 + (size_t)(b*1024 + (n>>1)) * D_;
  const u16* y2 = Y2 + (size_t)(b*512  + (n>>2)) * D_;
  float xv[4], wv[4];
  float ss = 0.f;
  #pragma unroll
  for (int t = 0; t < 4; t++) {
    int c = threadIdx.x + t*256;
    float v = p0*xr[c] + p1*(w0*bf2f(y0[c]) + w1*bf2f(y1[c]) + ww2*bf2f(y2[c]));
    xv[t] = v; wv[t] = w2[c]; ss += v*v;
    x1[(size_t)i*D_ + c] = v;
  }
  #pragma unroll
  for (int o = 1; o < 64; o <<= 1) ss += __shfl_xor(ss, o);
  __shared__ float red[4];
  if ((threadIdx.x & 63) == 0) red[threadIdx.x >> 6] = ss;
  __syncthreads();
  float sc = rsqrtf((red[0]+red[1]+red[2]+red[3]) * (1.f/D_) + 1e-6f);
  #pragma unroll
  for (int t = 0; t < 4; t++) {
    int c = threadIdx.x + t*256;
    xn2[(size_t)i*D_ + c] = f2bf(xv[t]*wv[t]*sc);
  }
}

// ================================ host launcher ================================
extern "C" void kernel_launch(void* const* d_in, const int* in_sizes, int n_in,
                              void* d_out, int out_size, void* d_ws, size_t ws_size,
                              hipStream_t stream) {
  (void)in_sizes; (void)n_in; (void)out_size; (void)ws_size;
  const float* x    = (const float*)d_in[0];
  const float* nw1  = (const float*)d_in[1];
  const float* nw2  = (const float*)d_in[2];
  const float* Wdec = (const float*)d_in[3];
  const float* Wq   = (const float*)d_in[4];
  const float* Wk   = (const float*)d_in[5];
  const float* Wv   = (const float*)d_in[6];
  const float* Wo   = (const float*)d_in[7];
  const float* agg  = (const float*)d_in[8];
  const float* Wg   = (const float*)d_in[9];
  const float* Wu   = (const float*)d_in[10];
  const float* Wdn  = (const float*)d_in[11];
  const float* mA   = (const float*)d_in[12];
  const float* mF   = (const float*)d_in[13];
  float* out = (float*)d_out;

  char* ws = (char*)d_ws;
  size_t off = 0;
  auto take = [&](size_t b) { size_t r = off; off += (b + 255) & ~(size_t)255; return r; };

  u16* A_wp  = (u16*)(ws + take((size_t)9216*1024*2));
  u16* WdecB = (u16*)(ws + take((size_t)3*1024*1024*2));
  u16* Wqkv  = (u16*)(ws + take((size_t)9216*1024*2));
  u16* BTgu  = (u16*)(ws + take((size_t)5632*1024*2));   // gate/up 16-col interleaved
  u16* WdnT  = (u16*)(ws + take((size_t)HIDP*1024*2));
  u16* WoT   = (u16*)(ws + take((size_t)1024*1024*2));
  u16* xn_all = (u16*)(ws + take((size_t)7168*1024*2));
  float* x1  = (float*)(ws + take((size_t)CNT*4));
  float* SCb = (float*)(ws + take(256));
  char*  big = ws + take(88080384);
  // attention phase
  u16*   QKV   = (u16*)big;                              // [7168, 2048] bf16 (Q|K)
  u16*   VTa   = (u16*)(big + 29360128);                 // per-level [b][1024][Nl]
  u16*   Ob    = (u16*)(big + 44040192);                 // [7168, 1024] bf16
  u16*   YC    = (u16*)(big + 58720256);                 // [7168, 1024] bf16
  // FFN phase alias (attention working set dead by then; YC region untouched)
  u16*   hbuf  = (u16*)big;                              // [4096, 2816] bf16

  dim3 blk(256);
  const int BIG = 1 << 30;

  // ---- 1: all weight prep in one launch (+ SCb zero) ----
  wprep_k<<<21760, blk, 0, stream>>>(Wdec, Wq, Wk, Wv, Wo, Wg, Wu, Wdn,
                                     A_wp, WdecB, WoT, BTgu, WdnT, SCb);
  // ---- 2: fused QKV weights: F_l^T = [Wq|Wk|Wv]_l^T x Wdec_l^T ----
  gemm_t<4,1><<<dim3(8, 72), blk, 0, stream>>>(A_wp, WdecB, Wqkv, nullptr, nullptr,
                                               1024, 1024, 24, 48, 1024u*1024u);
  // ---- 3: attention RMSNorm + both pools ----
  rmsA_k<<<1024, blk, 0, stream>>>(x, nw1, xn_all,
                                   xn_all + (size_t)4096*1024, xn_all + (size_t)6144*1024);
  // ---- 4: QK GEMM (per-level weight select), stride-2048 output ----
  gemm_t<4,1><<<dim3(16, 56), blk, 0, stream>>>(xn_all, Wqkv, QKV, nullptr, nullptr,
                                                2048, 1024, 32, 48, 3072u*1024u);
  // ---- 5: V^T GEMM (replaces V-projection + transpose), compact grid ----
  vgemm_k<<<448, blk, 0, stream>>>(Wqkv, xn_all, VTa);
  // ---- 6: flash attention (all levels) ----
  flash_k<<<896, blk, 0, stream>>>(QKV, VTa, Ob);
  // ---- 7: output projection -> YC (bf16) ----
  gemm_t<2,1><<<dim3(8, 112), blk, 0, stream>>>(Ob, WoT, YC, nullptr, nullptr,
                                                1024, 1024, BIG, BIG, 0u);
  // ---- 8-9: Gram (atomics only, no fences) + scalar head ----
  u16* YC1 = YC + (size_t)4096*1024;
  u16* YC2 = YC + (size_t)6144*1024;
  gram_k<<<1024, blk, 0, stream>>>(YC, YC1, YC2, SCb);
  head_k<<<1, 64, 0, stream>>>(SCb, agg, mA, mF, out + CNT);
  // ---- 10: mix1 + FFN RMSNorm fused ----
  mixrms_k<<<4096, blk, 0, stream>>>(x, YC, YC1, YC2, SCb, nw2, x1, xn_all);
  // ---- 11: gate/up GEMM with fused silu*mul epilogue ----
  gemm_t<4,3><<<dim3(44, 32), blk, 0, stream>>>(xn_all, BTgu, hbuf, nullptr, nullptr,
                                                5632, 1024, BIG, BIG, 0u);
  // ---- 12: down GEMM with fused final residual mix ----
  gemm_t<2,2><<<dim3(8, 64), blk, 0, stream>>>(hbuf, WdnT, out, x1, SCb,
                                               1024, HIDP, BIG, BIG, 0u);
}